// Round 11
// baseline (1435.288 us; speedup 1.0000x reference)
//
#include <hip/hip_runtime.h>
#include <cstdint>
#include <cstddef>

#define T_LEN 16384
#define BATCH 8
#define NLAYER 9

typedef _Float16 f16;
typedef __attribute__((ext_vector_type(8))) _Float16 f16x8;
typedef __attribute__((ext_vector_type(4))) _Float16 f16x4;
typedef __attribute__((ext_vector_type(4))) float f32x4;
#define MFMA_F16 __builtin_amdgcn_mfma_f32_16x16x32_f16

__device__ __forceinline__ float fast_sigmoid(float x) {
    return 1.0f / (1.0f + __expf(-x));
}
__device__ __forceinline__ float fast_tanh(float x) {
    return 1.0f - 2.0f / (__expf(2.0f * x) + 1.0f);
}

// ---------------------------------------------------------------------------
// Weight prepack, ROLE-SWAPPED (weights are the MFMA A-operand now):
//  wA'[l][n][k] (n=0..255 pre-channels, k=0..383 = tap*128+r, row-major 384)
//      = conv_w[l][n][r][tap]
//  wB'[l][n][k] (n=0..255 out-channels: res 0-127, skip 128-255; k=0..127)
//      n<128 -> out_w[l][n][k]; n>=128 -> output1_w[n-128][l*128+k]
// ---------------------------------------------------------------------------
__global__ __launch_bounds__(256) void prep_weights(
    const float* __restrict__ cw, const float* __restrict__ ow,
    const float* __restrict__ o1w, f16* __restrict__ wA, f16* __restrict__ wB)
{
    int n = blockIdx.x * 256 + threadIdx.x;
    const int NA = NLAYER * 256 * 384;   // 884736
    const int NB = NLAYER * 256 * 128;   // 294912
    if (n < NA) {
        int k = n % 384; int q = n / 384;
        int c = q & 255; int l = q >> 8;
        int tap = k >> 7, r = k & 127;
        wA[n] = (f16)cw[((size_t)(l * 256 + c) * 128 + r) * 3 + tap];
    } else if (n < NA + NB) {
        int m = n - NA;
        int k = m & 127; int q = m >> 7;
        int c = q & 255; int l = q >> 8;
        float v = (c < 128) ? ow[(size_t)(l * 128 + c) * 128 + k]
                            : o1w[(size_t)(c - 128) * 1152 + l * 128 + k];
        wB[m] = (f16)v;
    }
}

// h[b][t][r] = tanh(iw[r]*x[b][t] + ib[r]) (fp16);  acc1 zero-init (fp16)
__global__ __launch_bounds__(256) void input_init(
    const float* __restrict__ x, const float* __restrict__ iw,
    const float* __restrict__ ib,
    f16* __restrict__ h, f16* __restrict__ acc1)
{
    int n = blockIdx.x * 256 + threadIdx.x;
    int r = n & 127; int bt = n >> 7;
    h[n] = (f16)fast_tanh(iw[r] * x[bt] + ib[r]);
    acc1[n] = (f16)0.0f;
}

// ---------------------------------------------------------------------------
// Kernel A: pre = h*WA + gating -> z.  Grid (16 strips, 2 halves, 8 batch)
// = 256 blocks of 512 thr (8 waves = 2 mg x 4 tg); block owns channel half
// hh: filters [hh*64,+64) + gates [128+hh*64,+64) -> WA slice 128 rows x 384
// persistent in LDS (98 KB, padded rows 392). t-loop: 4 iters x 256 t.
// Wave tile: M=64 pre-ch (mt 0,1 = filter tiles; 2,3 = paired gate tiles) x
// N=64 t. A-frags from LDS (conflict-free: stride 392), B-frags (h) direct
// from global 16B. Gating in registers (pairs same-wave), z written as 8-B
// stores. ZERO barriers after the initial weight load.
// ---------------------------------------------------------------------------
__global__ __launch_bounds__(512, 2) void layerA_kernel(
    const f16* __restrict__ h, f16* __restrict__ z,
    const f16* __restrict__ wA,   // [256][384] this layer
    const float* __restrict__ cb, // conv_b [256]
    int d)
{
    __shared__ __align__(16) f16 ws[128 * 392];   // 98 KB

    const int tid  = threadIdx.x;
    const int lane = tid & 63;
    const int w8   = tid >> 6;
    const int mg   = w8 & 1;          // channel sub-half (32 pairs)
    const int tg   = w8 >> 1;         // t-quarter within iteration
    const int col  = lane & 15;
    const int quad = lane >> 4;
    const int strip = blockIdx.x;
    const int hh    = blockIdx.y;
    const int b     = blockIdx.z;

    // ---- persistent weight load: 128 local rows x 384 k (pad 392) ----
#pragma unroll
    for (int i = 0; i < 12; ++i) {
        int u  = i * 512 + tid;
        int lr = u / 48;
        int g  = u % 48;
        int n  = (lr < 64) ? (hh * 64 + lr) : (128 + hh * 64 + (lr - 64));
        *(f16x8*)&ws[lr * 392 + g * 8] = *(const f16x8*)&wA[(size_t)n * 384 + g * 8];
    }
    __syncthreads();

    // per-lane biases (filter tile pair mtp: filter acc[mtp], gate acc[mtp+2])
    float cbF[2][4], cbG[2][4];
#pragma unroll
    for (int mtp = 0; mtp < 2; ++mtp)
#pragma unroll
        for (int r = 0; r < 4; ++r) {
            int c = hh * 64 + mg * 32 + mtp * 16 + quad * 4 + r;
            cbF[mtp][r] = cb[c];
            cbG[mtp][r] = cb[128 + c];
        }

    const f16* hb = h + (size_t)b * T_LEN * 128;
    f16* zb = z + (size_t)b * T_LEN * 128;

    for (int iter = 0; iter < 4; ++iter) {
        const int t0 = strip * 1024 + iter * 256 + tg * 64;

        f32x4 acc[4][4];
#pragma unroll
        for (int mt = 0; mt < 4; ++mt)
#pragma unroll
            for (int nt = 0; nt < 4; ++nt) acc[mt][nt] = (f32x4)0.0f;

#pragma unroll
        for (int ch = 0; ch < 12; ++ch) {
            const int tap = ch >> 2;
            const int off = (2 - tap) * d;
            const int kb  = (ch & 3) * 32 + quad * 8;
            f16x8 bv[4];
#pragma unroll
            for (int nt = 0; nt < 4; ++nt) {
                int t = t0 + nt * 16 + col - off;
                bv[nt] = (t >= 0) ? *(const f16x8*)&hb[(size_t)t * 128 + kb]
                                  : (f16x8)(f16)0.0f;
            }
            f16x8 av[4];
#pragma unroll
            for (int mt = 0; mt < 4; ++mt) {
                int lr = (mt < 2) ? (mg * 32 + mt * 16)
                                  : (64 + mg * 32 + (mt - 2) * 16);
                av[mt] = *(const f16x8*)&ws[(lr + col) * 392 + ch * 32 + quad * 8];
            }
#pragma unroll
            for (int mt = 0; mt < 4; ++mt)
#pragma unroll
                for (int nt = 0; nt < 4; ++nt)
                    acc[mt][nt] = MFMA_F16(av[mt], bv[nt], acc[mt][nt], 0, 0, 0);
        }

        // gating in registers -> z (8-B stores, D[m=out-ch quad*4+reg][n=t col])
#pragma unroll
        for (int nt = 0; nt < 4; ++nt) {
            int t = t0 + nt * 16 + col;
#pragma unroll
            for (int mtp = 0; mtp < 2; ++mtp) {
                f16x4 zv;
#pragma unroll
                for (int r = 0; r < 4; ++r) {
                    float f = acc[mtp][nt][r]     + cbF[mtp][r];
                    float g = acc[mtp + 2][nt][r] + cbG[mtp][r];
                    zv[r] = (f16)(fast_tanh(f) * fast_sigmoid(g));
                }
                *(f16x4*)&zb[(size_t)t * 128 + hh * 64 + mg * 32 + mtp * 16 + quad * 4] = zv;
            }
        }
    }
}

// ---------------------------------------------------------------------------
// Kernel B: [res|skip] = z*WB'; h_out = h_in + res + ob; acc1 += skip.
// Grid 2048 blocks x 256 thr (4 waves = 4 out-channel quarters mg).
// Wave tile M=64 out-ch x N=64 t. A-frags = weights direct from L2 (64 KB,
// hot), B-frags = z direct from global (16B). NO LDS, NO barriers.
// Epilogue in registers: 8-B read-modify-write per (mt,nt).
// ---------------------------------------------------------------------------
__global__ __launch_bounds__(256, 3) void layerB_kernel(
    const f16* __restrict__ z, const f16* __restrict__ h_in,
    f16* __restrict__ h_out, f16* __restrict__ acc1,
    const f16* __restrict__ wB,   // [256][128] this layer
    const float* __restrict__ ob) // out_b [128]
{
    const int tid  = threadIdx.x;
    const int lane = tid & 63;
    const int mg   = tid >> 6;        // out-channel quarter: 0,1=res 2,3=skip
    const int col  = lane & 15;
    const int quad = lane >> 4;
    const size_t bt0 = (size_t)blockIdx.x * 64;

    const bool isRes = (mg < 2);
    float obv[4][4];
#pragma unroll
    for (int mt = 0; mt < 4; ++mt)
#pragma unroll
        for (int r = 0; r < 4; ++r)
            obv[mt][r] = isRes ? ob[mg * 64 + mt * 16 + quad * 4 + r] : 0.0f;

    f32x4 acc[4][4];
#pragma unroll
    for (int mt = 0; mt < 4; ++mt)
#pragma unroll
        for (int nt = 0; nt < 4; ++nt) acc[mt][nt] = (f32x4)0.0f;

#pragma unroll
    for (int ch = 0; ch < 4; ++ch) {
        f16x8 bv[4];
#pragma unroll
        for (int nt = 0; nt < 4; ++nt)
            bv[nt] = *(const f16x8*)&z[(bt0 + nt * 16 + col) * 128 + ch * 32 + quad * 8];
        f16x8 av[4];
#pragma unroll
        for (int mt = 0; mt < 4; ++mt)
            av[mt] = *(const f16x8*)&wB[(size_t)(mg * 64 + mt * 16 + col) * 128 + ch * 32 + quad * 8];
#pragma unroll
        for (int mt = 0; mt < 4; ++mt)
#pragma unroll
            for (int nt = 0; nt < 4; ++nt)
                acc[mt][nt] = MFMA_F16(av[mt], bv[nt], acc[mt][nt], 0, 0, 0);
    }

#pragma unroll
    for (int nt = 0; nt < 4; ++nt) {
        size_t bt = bt0 + nt * 16 + col;
#pragma unroll
        for (int mt = 0; mt < 4; ++mt) {
            int ch4 = mg * 64 + mt * 16 + quad * 4;
            if (isRes) {
                size_t a = bt * 128 + ch4;
                f16x4 hv = *(const f16x4*)&h_in[a];
                f16x4 o;
#pragma unroll
                for (int r = 0; r < 4; ++r)
                    o[r] = (f16)((float)hv[r] + acc[mt][nt][r] + obv[mt][r]);
                *(f16x4*)&h_out[a] = o;
            } else {
                size_t a = bt * 128 + (ch4 - 128);
                f16x4 av2 = *(const f16x4*)&acc1[a];
                f16x4 o;
#pragma unroll
                for (int r = 0; r < 4; ++r)
                    o[r] = (f16)((float)av2[r] + acc[mt][nt][r]);
                *(f16x4*)&acc1[a] = o;
            }
        }
    }
}

// out[bt] = o2b + sum_r o2w[r] * tanh(acc1[bt][r] + o1b[r]); one wave per bt
__global__ __launch_bounds__(256) void final_kernel(
    const f16* __restrict__ acc1, const float* __restrict__ b1,
    const float* __restrict__ w2, const float* __restrict__ b2,
    float* __restrict__ out)
{
    int lane = threadIdx.x & 63;
    int w = threadIdx.x >> 6;
    int bt = blockIdx.x * 4 + w;
    float v0 = (float)acc1[(size_t)bt * 128 + lane];
    float v1 = (float)acc1[(size_t)bt * 128 + lane + 64];
    float s = w2[lane] * fast_tanh(v0 + b1[lane]) +
              w2[lane + 64] * fast_tanh(v1 + b1[lane + 64]);
#pragma unroll
    for (int k = 1; k < 64; k <<= 1) s += __shfl_xor(s, k, 64);
    if (lane == 0) out[bt] = s + b2[0];
}

extern "C" void kernel_launch(void* const* d_in, const int* in_sizes, int n_in,
                              void* d_out, int out_size, void* d_ws, size_t ws_size,
                              hipStream_t stream)
{
    const float* x   = (const float*)d_in[0];
    const float* iw  = (const float*)d_in[1];
    const float* ib  = (const float*)d_in[2];
    const float* cw  = (const float*)d_in[3];
    const float* cb  = (const float*)d_in[4];
    const float* ow  = (const float*)d_in[5];
    const float* ob  = (const float*)d_in[6];
    const float* o1w = (const float*)d_in[7];
    const float* o1b = (const float*)d_in[8];
    const float* o2w = (const float*)d_in[9];
    const float* o2b = (const float*)d_in[10];
    float* out = (float*)d_out;

    const size_t HTR = (size_t)BATCH * T_LEN * 128;   // 16777216
    f16* hA   = (f16*)d_ws;
    f16* hB   = hA + HTR;
    f16* acc1 = hB + HTR;
    f16* zbuf = acc1 + HTR;
    f16* wAp  = zbuf + HTR;
    f16* wBp  = wAp + (size_t)NLAYER * 256 * 384;
    // total ~ 4*32 MB + 2.4 MB = ~134 MB of ws

    prep_weights<<<4608, 256, 0, stream>>>(cw, ow, o1w, wAp, wBp);
    input_init<<<65536, 256, 0, stream>>>(x, iw, ib, hA, acc1);

    const int DIL[NLAYER] = {1, 2, 4, 8, 16, 32, 64, 128, 256};
    f16* hin = hA; f16* hout = hB;
    for (int l = 0; l < NLAYER; ++l) {
        layerA_kernel<<<dim3(16, 2, BATCH), 512, 0, stream>>>(
            hin, zbuf, wAp + (size_t)l * 256 * 384, cb + l * 256, DIL[l]);
        layerB_kernel<<<BATCH * T_LEN / 64, 256, 0, stream>>>(
            zbuf, hin, hout, acc1, wBp + (size_t)l * 256 * 128, ob + l * 128);
        f16* tmp = hin; hin = hout; hout = tmp;
    }
    final_kernel<<<BATCH * T_LEN / 4, 256, 0, stream>>>(acc1, o1b, o2w, o2b, out);
}

// Round 12
// 916.173 us; speedup vs baseline: 1.5666x; 1.5666x over previous
//
#include <hip/hip_runtime.h>
#include <cstdint>
#include <cstddef>

#define T_LEN 16384
#define BATCH 8
#define NLAYER 9

typedef _Float16 f16;
typedef __attribute__((ext_vector_type(8))) _Float16 f16x8;
typedef __attribute__((ext_vector_type(4))) float f32x4;
#define MFMA_F16 __builtin_amdgcn_mfma_f32_16x16x32_f16

// s_waitcnt imm encoding (gfx9/CDNA): vmcnt[3:0] | expcnt(7=nowait)<<4 | lgkmcnt(0xF=nowait)<<8
#define WAIT_VM8 0xF78
#define WAIT_VM0 0xF70

__device__ __forceinline__ float fast_sigmoid(float x) {
    return 1.0f / (1.0f + __expf(-x));
}
__device__ __forceinline__ float fast_tanh(float x) {
    return 1.0f - 2.0f / (__expf(2.0f * x) + 1.0f);
}

// async global->LDS DMA, 16 B per lane (dst = wave-uniform base + lane*16)
__device__ __forceinline__ void stage16(const f16* g, f16* l) {
    __builtin_amdgcn_global_load_lds(
        (const __attribute__((address_space(1))) unsigned int*)g,
        (__attribute__((address_space(3))) unsigned int*)l, 16, 0, 0);
}

// ---------------------------------------------------------------------------
// Weight prepack to fp16.
//  wA: per-wave-slice layout [l][ch12][w4][r64][kp32], PRE-SWIZZLED within a
//   row (slot i holds logical slot i ^ ((r>>1)&3)) so a linear DMA copy gives
//   the conflict-free LDS image. Row r<32 -> filter ch w*32+r; r>=32 -> gate
//   128+w*32+(r-32). k-mapping per chunk: tap=ch>>2, h-channel=(ch&3)*32+kp.
//  wB: linear [l][ch4][n256][kp32] (phase-2 reads direct from L2).
// ---------------------------------------------------------------------------
__global__ __launch_bounds__(256) void prep_weights(
    const float* __restrict__ cw, const float* __restrict__ ow,
    const float* __restrict__ o1w, f16* __restrict__ wA, f16* __restrict__ wB)
{
    int n = blockIdx.x * 256 + threadIdx.x;
    const int NA = NLAYER * 12 * 4 * 64 * 32;   // 884736
    const int NB = NLAYER * 4 * 256 * 32;       // 294912
    if (n < NA) {
        int kp = n & 31; int q = n >> 5;
        int r = q & 63;  q >>= 6;
        int w = q & 3;   q >>= 2;
        int ch = q % 12; int l = q / 12;
        int i = kp >> 3, j = kp & 7;
        int kpl = (i ^ ((r >> 1) & 3)) * 8 + j;        // undo read-side swizzle
        int c = (r < 32) ? (w * 32 + r) : (128 + w * 32 + (r - 32));
        int rh = (ch & 3) * 32 + kpl;
        int tap = ch >> 2;
        wA[n] = (f16)cw[((size_t)(l * 256 + c) * 128 + rh) * 3 + tap];
    } else if (n < NA + NB) {
        int m = n - NA;
        int kp = m & 31; int q = m >> 5;
        int c = q & 255; q >>= 8;
        int ch = q & 3;  int l = q >> 2;
        int k = ch * 32 + kp;
        float v = (c < 128) ? ow[(size_t)(l * 128 + c) * 128 + k]
                            : o1w[(size_t)(c - 128) * 1152 + l * 128 + k];
        wB[m] = (f16)v;
    }
}

// h[b][t][r] = tanh(iw[r]*x[b][t] + ib[r]) (fp16);  acc1 zero-init (fp16)
__global__ __launch_bounds__(256) void input_init(
    const float* __restrict__ x, const float* __restrict__ iw,
    const float* __restrict__ ib,
    f16* __restrict__ h, f16* __restrict__ acc1)
{
    int n = blockIdx.x * 256 + threadIdx.x;
    int r = n & 127; int bt = n >> 7;
    h[n] = (f16)fast_tanh(iw[r] * x[bt] + ib[r]);
    acc1[n] = (f16)0.0f;
}

// ---------------------------------------------------------------------------
// One layer. Block 256 thr = 4 waves, all covering rows t0..t0+64; wave w
// owns 64 channels (filters [w*32,+32) paired with gates [128+w*32,+32)).
// Wave tile M=64 (4 mt) x N=64 (4 nt: 0,1=filter 2,3=gate) -> 4 MFMAs/B-frag.
// Phase 1 K-loop: wave-private double-buffered DMA staging, NO barriers —
// readiness via explicit s_waitcnt vmcnt(8) (2-iteration pipeline; A-loads
// unconditional+clamped so the vm-op count per iteration is exact).
// Phase 2: B direct from L2. 3 barriers total. LDS 50 KB -> 3 blocks/CU.
// ---------------------------------------------------------------------------
__global__ __launch_bounds__(256, 3) void layer_kernel(
    const f16* __restrict__ h_in, f16* __restrict__ h_out,
    f16* __restrict__ acc1,
    const f16* __restrict__ wA,   // [12][4][64][32] this layer (pre-swizzled)
    const f16* __restrict__ wB,   // [4][256][32]  this layer (linear)
    const float* __restrict__ cb, // conv_b [256]
    const float* __restrict__ ob, // out_b  [128]
    int d)
{
    __shared__ __align__(16) f16 bufs[4][2][2048];   // 32 KB wave-private dbuf
    __shared__ __align__(16) f16 zs[64 * 136];       // 17.4 KB

    const int tid  = threadIdx.x;
    const int lane = tid & 63;
    const int w    = tid >> 6;
    const int col  = lane & 15;
    const int quad = lane >> 4;
    const int b    = blockIdx.y;
    const int t0   = blockIdx.x * 64;

    const f16* hb = h_in + (size_t)b * T_LEN * 128;
    const int bswz = (quad ^ ((col >> 1) & 3)) * 8;

    f32x4 acc[4][4];
#pragma unroll
    for (int mt = 0; mt < 4; ++mt)
#pragma unroll
        for (int nt = 0; nt < 4; ++nt) acc[mt][nt] = (f32x4)0.0f;

    f16x8 areg[3][4];

    // issue wave's DMA for chunk ch -> bufs[w][ch&1]  (4 vm-ops, fixed)
    auto dmaB = [&](int ch) {
        const f16* src = wA + (size_t)(ch * 4 + w) * 2048 + lane * 8;
        f16* dst = &bufs[w][ch & 1][0];
#pragma unroll
        for (int i = 0; i < 4; ++i) stage16(src + i * 512, dst + i * 512);
    };
    // A-loads for chunk ch (4 vm-ops, fixed: unconditional, clamped address)
    auto loadA = [&](int ch, f16x8* dst) {
        const int tap = ch >> 2;
        const int off = (2 - tap) * d;
        const int kb  = (ch & 3) * 32 + quad * 8;
#pragma unroll
        for (int mt = 0; mt < 4; ++mt) {
            int t  = t0 + mt * 16 + col - off;
            int tc = t < 0 ? 0 : t;
            f16x8 v = *(const f16x8*)&hb[(size_t)tc * 128 + kb];
            dst[mt] = t < 0 ? (f16x8)(f16)0.0f : v;
        }
    };
    // consume chunk ch (ds_read 4 B-frags + 16 MFMAs), optionally issue ch+2
    auto p1body = [&](int ch, bool issue) {
        const f16* bsc = &bufs[w][ch & 1][0];
        f16x8 bf[4];
#pragma unroll
        for (int nt = 0; nt < 4; ++nt) {
            int lr = (nt < 2) ? (nt * 16 + col) : (32 + (nt - 2) * 16 + col);
            bf[nt] = *(const f16x8*)&bsc[lr * 32 + bswz];
        }
        if (issue) { dmaB(ch + 2); loadA(ch + 2, areg[(ch + 2) % 3]); }
        f16x8* ar = areg[ch % 3];
#pragma unroll
        for (int nt = 0; nt < 4; ++nt)
#pragma unroll
            for (int mt = 0; mt < 4; ++mt)
                acc[mt][nt] = MFMA_F16(ar[mt], bf[nt], acc[mt][nt], 0, 0, 0);
    };

    // ---------------- Phase 1: K=384, 12 chunks, barrier-free ---------------
    dmaB(0); loadA(0, areg[0]);
    dmaB(1); loadA(1, areg[1]);
#pragma unroll
    for (int ch = 0; ch < 10; ++ch) {
        __builtin_amdgcn_s_waitcnt(WAIT_VM8);   // retire chunk-ch DMA + A group
        p1body(ch, true);
    }
    __builtin_amdgcn_s_waitcnt(WAIT_VM8);
    p1body(10, false);
    __builtin_amdgcn_s_waitcnt(WAIT_VM0);
    p1body(11, false);

    // ---------------- Gating (in registers) -> zs ---------------------------
#pragma unroll
    for (int nt = 0; nt < 2; ++nt) {
        int j = w * 32 + nt * 16 + col;
        float cf = cb[j];
        float cg = cb[j + 128];
#pragma unroll
        for (int mt = 0; mt < 4; ++mt)
#pragma unroll
            for (int reg = 0; reg < 4; ++reg) {
                float f = acc[mt][nt][reg]     + cf;
                float g = acc[mt][nt + 2][reg] + cg;
                zs[(mt * 16 + quad * 4 + reg) * 136 + j] =
                    (f16)(fast_tanh(f) * fast_sigmoid(g));
            }
    }
    __syncthreads();   // all z columns visible; bufs now dead everywhere

    // ---------------- Phase 2: [res|skip] = z * WB, K=128 -------------------
#pragma unroll
    for (int mt = 0; mt < 4; ++mt)
#pragma unroll
        for (int nt = 0; nt < 4; ++nt) acc[mt][nt] = (f32x4)0.0f;

#pragma unroll
    for (int ch = 0; ch < 4; ++ch) {
        f16x8 a[4];
#pragma unroll
        for (int mt = 0; mt < 4; ++mt)
            a[mt] = *(const f16x8*)&zs[(mt * 16 + col) * 136 + ch * 32 + quad * 8];
        const f16* wc = wB + ch * 8192;
#pragma unroll
        for (int nt = 0; nt < 4; ++nt) {
            int nb = (nt < 2) ? (w * 32 + nt * 16)
                              : (128 + w * 32 + (nt - 2) * 16);
            f16x8 bf = *(const f16x8*)&wc[(nb + col) * 32 + quad * 8];
#pragma unroll
            for (int mt = 0; mt < 4; ++mt)
                acc[mt][nt] = MFMA_F16(a[mt], bf, acc[mt][nt], 0, 0, 0);
        }
    }
    __syncthreads();   // zs reads drained before overwrite

    // ---------------- Epilogue transposes: res -> zs, skip -> bufs ----------
    f16* sk = &bufs[0][0][0];   // reuse as [64][136]
#pragma unroll
    for (int nt = 0; nt < 2; ++nt) {
        int n = w * 32 + nt * 16 + col;
        float o = ob[n];
#pragma unroll
        for (int mt = 0; mt < 4; ++mt)
#pragma unroll
            for (int reg = 0; reg < 4; ++reg) {
                int row = mt * 16 + quad * 4 + reg;
                zs[row * 136 + n] = (f16)(acc[mt][nt][reg] + o);
                sk[row * 136 + n] = (f16)acc[mt][nt + 2][reg];
            }
    }
    __syncthreads();

    const int orow = tid >> 2, oseg = tid & 3;
    const size_t gb = (size_t)b * T_LEN * 128 + (size_t)(t0 + orow) * 128 + oseg * 32;
#pragma unroll
    for (int i = 0; i < 4; ++i) {
        f16x8 rv = *(const f16x8*)&zs[orow * 136 + oseg * 32 + i * 8];
        f16x8 hv = *(const f16x8*)&h_in[gb + i * 8];
        *(f16x8*)&h_out[gb + i * 8] = hv + rv;
    }
#pragma unroll
    for (int i = 0; i < 4; ++i) {
        f16x8 sv = *(const f16x8*)&sk[orow * 136 + oseg * 32 + i * 8];
        f16x8 av = *(const f16x8*)&acc1[gb + i * 8];
        *(f16x8*)&acc1[gb + i * 8] = av + sv;
    }
}

// out[bt] = o2b + sum_r o2w[r] * tanh(acc1[bt][r] + o1b[r]); one wave per bt
__global__ __launch_bounds__(256) void final_kernel(
    const f16* __restrict__ acc1, const float* __restrict__ b1,
    const float* __restrict__ w2, const float* __restrict__ b2,
    float* __restrict__ out)
{
    int lane = threadIdx.x & 63;
    int w = threadIdx.x >> 6;
    int bt = blockIdx.x * 4 + w;
    float v0 = (float)acc1[(size_t)bt * 128 + lane];
    float v1 = (float)acc1[(size_t)bt * 128 + lane + 64];
    float s = w2[lane] * fast_tanh(v0 + b1[lane]) +
              w2[lane + 64] * fast_tanh(v1 + b1[lane + 64]);
#pragma unroll
    for (int k = 1; k < 64; k <<= 1) s += __shfl_xor(s, k, 64);
    if (lane == 0) out[bt] = s + b2[0];
}

extern "C" void kernel_launch(void* const* d_in, const int* in_sizes, int n_in,
                              void* d_out, int out_size, void* d_ws, size_t ws_size,
                              hipStream_t stream)
{
    const float* x   = (const float*)d_in[0];
    const float* iw  = (const float*)d_in[1];
    const float* ib  = (const float*)d_in[2];
    const float* cw  = (const float*)d_in[3];
    const float* cb  = (const float*)d_in[4];
    const float* ow  = (const float*)d_in[5];
    const float* ob  = (const float*)d_in[6];
    const float* o1w = (const float*)d_in[7];
    const float* o1b = (const float*)d_in[8];
    const float* o2w = (const float*)d_in[9];
    const float* o2b = (const float*)d_in[10];
    float* out = (float*)d_out;

    const size_t HTR = (size_t)BATCH * T_LEN * 128;   // 16777216
    f16* hA   = (f16*)d_ws;
    f16* hB   = hA + HTR;
    f16* acc1 = hB + HTR;
    f16* wAp  = acc1 + HTR;
    f16* wBp  = wAp + (size_t)NLAYER * 12 * 4 * 64 * 32;
    // total ~ 3*32 MB + 2.4 MB = ~103 MB of ws

    prep_weights<<<4608, 256, 0, stream>>>(cw, ow, o1w, wAp, wBp);
    input_init<<<65536, 256, 0, stream>>>(x, iw, ib, hA, acc1);

    const int DIL[NLAYER] = {1, 2, 4, 8, 16, 32, 64, 128, 256};
    f16* hin = hA; f16* hout = hB;
    for (int l = 0; l < NLAYER; ++l) {
        layer_kernel<<<dim3(T_LEN / 64, BATCH), 256, 0, stream>>>(
            hin, hout, acc1,
            wAp + (size_t)l * 12 * 4 * 64 * 32, wBp + (size_t)l * 4 * 256 * 32,
            cb + l * 256, ob + l * 128, DIL[l]);
        f16* tmp = hin; hin = hout; hout = tmp;
    }
    final_kernel<<<BATCH * T_LEN / 4, 256, 0, stream>>>(acc1, o1b, o2w, o2b, out);
}